// Round 10
// baseline (933.341 us; speedup 1.0000x reference)
//
#include <hip/hip_runtime.h>
#include <hip/hip_cooperative_groups.h>
#include <math.h>

namespace cg = cooperative_groups;

#define BB 512
#define SS 50
#define EE 128
#define HH 8
#define RR 32
#define NC 5
#define NSEQ 20000
#define NBS (BB*SS)   // 25600
#define LDK 136       // padded bf16 row stride (ushorts) for LDS A-tile
#define GRID 768      // 3 blocks/CU guaranteed co-resident (LDS 25KB, VGPR<=128)
#define SCANB 79      // ceil(NSEQ/256)

typedef __attribute__((ext_vector_type(8))) __bf16 bf16x8;
typedef __attribute__((ext_vector_type(4))) float f32x4;
typedef __attribute__((ext_vector_type(4))) unsigned short us4;

__device__ __forceinline__ unsigned short f2bf(float f) {
    unsigned int u = __float_as_uint(f);
    unsigned int r = (u + 0x7fffu + ((u >> 16) & 1u)) >> 16;
    return (unsigned short)r;
}
__device__ __forceinline__ float dot44(const f32x4& a, const f32x4& b) {
    return a[0]*b[0] + a[1]*b[1] + a[2]*b[2] + a[3]*b[3];
}

struct Params {
    const int *user, *item, *neighbor, *seq;
    const float *uet, *iet, *ui_lcu, *iu_lcu;
    const float *wq, *bq, *wk, *bk, *wv, *bv, *wo, *bo, *fcw, *fcb;
    float *ws_ne2, *ws_np, *ws_ip;
    unsigned short *wvT, *woT;
    int *hist, *jlist, *jstart, *Mcount, *pinfo, *pitem, *blockSum, *blockNz;
    float *out;
};

union SMem {
    struct { int ws[4], wz[4]; } scan;
    struct {
        unsigned short kA[64*LDK];
        unsigned short qkvT[16][EE];
        float ue[EE];
        float qs[EE];
        float qkb[HH];
        float attn[HH][64];
        float maskadd[64];
    } a;
    struct { float part[8][RR]; float urv[RR]; float lg[NC]; } h;
};

__global__ __launch_bounds__(256, 4) void mega_kernel(Params p) {
    cg::grid_group grid = cg::this_grid();
    __shared__ SMem sm;
    const int t   = threadIdx.x;
    const int bid = blockIdx.x;
    const int gid = bid * 256 + t;

    // ================= P0: init — zero hist, convert/transpose wv,wo =================
    if (gid < NSEQ) p.hist[gid] = 0;
    for (int idx = gid; idx < EE*EE; idx += GRID*256) {
        const int n = idx >> 7, k = idx & 127;
        p.wvT[idx] = f2bf(p.wv[k*EE + n]);
        p.woT[idx] = f2bf(p.wo[k*EE + n]);
    }
    grid.sync();

    // ================= P1: histogram of seq =================
    if (gid < NBS) atomicAdd(&p.hist[p.seq[gid]], 1);
    grid.sync();

    // ================= P2a: block-local scans (counts + nonzero flags) =================
    int v = 0, nzv = 0, incl = 0, inclz = 0;
    if (bid < SCANB) {
        const int i = bid * 256 + t;
        v   = (i < NSEQ) ? p.hist[i] : 0;
        nzv = (v > 0) ? 1 : 0;
        incl = v; inclz = nzv;
        #pragma unroll
        for (int off = 1; off < 64; off <<= 1) {
            int a1 = __shfl_up(incl, off);
            int a2 = __shfl_up(inclz, off);
            if ((t & 63) >= off) { incl += a1; inclz += a2; }
        }
        if ((t & 63) == 63) { sm.scan.ws[t >> 6] = incl; sm.scan.wz[t >> 6] = inclz; }
        __syncthreads();
        if (t == 0) {
            int a = 0, b2 = 0;
            #pragma unroll
            for (int k = 0; k < 4; ++k) {
                int x = sm.scan.ws[k], y = sm.scan.wz[k];
                sm.scan.ws[k] = a; sm.scan.wz[k] = b2;
                a += x; b2 += y;
            }
            p.blockSum[bid] = a; p.blockNz[bid] = b2;
        }
        __syncthreads();
        incl  += sm.scan.ws[t >> 6];   // block-level inclusive
        inclz += sm.scan.wz[t >> 6];
        __syncthreads();               // done with sm.scan before attn reuses LDS
    }
    grid.sync();

    // ================= P2b: top-level scan of block totals (block 0) =================
    if (bid == 0 && t == 0) {
        int a = 0;
        for (int k = 0; k < SCANB; ++k) { int x = p.blockSum[k]; p.blockSum[k] = a; a += x; }
    }
    if (bid == 0 && t == 1) {
        int a = 0;
        for (int k = 0; k < SCANB; ++k) { int x = p.blockNz[k]; p.blockNz[k] = a; a += x; }
        p.Mcount[0] = a;
        p.jstart[a] = NBS;             // sentinel
    }
    grid.sync();

    // ================= P2c: write exclusive offsets + compacted jlist/jstart =================
    if (bid < SCANB) {
        const int i = bid * 256 + t;
        if (i < NSEQ) {
            const int excl = p.blockSum[bid] + incl - v;
            p.hist[i] = excl;          // working offsets for scatter
            if (v > 0) {
                const int slot = p.blockNz[bid] + inclz - 1;
                p.jlist[slot]  = i;
                p.jstart[slot] = excl;
            }
        }
    }
    grid.sync();

    // ================= P3: scatter — group occurrences by j =================
    if (gid < NBS) {
        const int pos = atomicAdd(&p.hist[p.seq[gid]], 1);
        p.pinfo[pos] = gid | ((p.neighbor[gid] > 0) ? 0 : 0x80000000);
        p.pitem[pos] = p.item[(unsigned)gid / SS];
    }
    grid.sync();

    const int r = t >> 3, l = t & 7;

    // ================= P4: attn (blocks 0..511)  ||  ip-half region (512..767) =================
    if (bid < BB) {
        // ---------------- attention, all-MFMA (verified r6 code) ----------------
        const int b = bid;
        if (t < EE) sm.a.ue[t] = p.uet[(size_t)p.user[b]*EE + t];
        if (t < 64) sm.a.maskadd[t] = (t < SS && p.neighbor[b*SS + t] > 0) ? 0.f : -1e9f;
        for (int idx = t; idx < SS*32; idx += 256) {
            int s = idx >> 5, g = idx & 31;
            float4 vv = ((const float4*)(p.uet + (size_t)p.neighbor[b*SS + s]*EE))[g];
            us4 o; o.x = f2bf(vv.x); o.y = f2bf(vv.y); o.z = f2bf(vv.z); o.w = f2bf(vv.w);
            *(us4*)&sm.a.kA[s*LDK + g*4] = o;
        }
        for (int idx = t; idx < 14*LDK; idx += 256) sm.a.kA[50*LDK + idx] = 0;
        for (int idx = t; idx < 8*EE; idx += 256) sm.a.qkvT[8 + (idx >> 7)][idx & 127] = 0;
        __syncthreads();

        if (t < EE) {
            float acc = p.bq[t];
            #pragma unroll 4
            for (int e = 0; e < EE; ++e) acc = fmaf(sm.a.ue[e], p.wq[e*EE + t], acc);
            sm.a.qs[t] = acc;
        }
        __syncthreads();

        {
            const int e = t >> 1, h0 = (t & 1) * 4;
            const float* wrow = p.wk + e*EE;
            #pragma unroll
            for (int j = 0; j < 4; ++j) {
                int h = h0 + j;
                float acc = 0.f;
                #pragma unroll
                for (int d = 0; d < 16; ++d) acc = fmaf(sm.a.qs[h*16 + d], wrow[h*16 + d], acc);
                sm.a.qkvT[h][e] = f2bf(acc);
            }
        }
        if (t < HH) {
            float acc = 0.f;
            #pragma unroll
            for (int d = 0; d < 16; ++d) acc = fmaf(sm.a.qs[t*16 + d], p.bk[t*16 + d], acc);
            sm.a.qkb[t] = acc;
        }
        __syncthreads();

        const int w    = t >> 6;
        const int ll   = t & 63;
        const int lrow = ll & 15;
        const int kg   = ll >> 4;

        bf16x8 a0 = *(const bf16x8*)&sm.a.kA[(w*16 + lrow)*LDK +  0 + kg*8];
        bf16x8 a1 = *(const bf16x8*)&sm.a.kA[(w*16 + lrow)*LDK + 32 + kg*8];
        bf16x8 a2 = *(const bf16x8*)&sm.a.kA[(w*16 + lrow)*LDK + 64 + kg*8];
        bf16x8 a3 = *(const bf16x8*)&sm.a.kA[(w*16 + lrow)*LDK + 96 + kg*8];

        {
            bf16x8 b0 = *(const bf16x8*)&sm.a.qkvT[lrow][ 0 + kg*8];
            bf16x8 b1 = *(const bf16x8*)&sm.a.qkvT[lrow][32 + kg*8];
            bf16x8 b2 = *(const bf16x8*)&sm.a.qkvT[lrow][64 + kg*8];
            bf16x8 b3 = *(const bf16x8*)&sm.a.qkvT[lrow][96 + kg*8];
            f32x4 c = {0.f, 0.f, 0.f, 0.f};
            c = __builtin_amdgcn_mfma_f32_16x16x32_bf16(a0, b0, c, 0, 0, 0);
            c = __builtin_amdgcn_mfma_f32_16x16x32_bf16(a1, b1, c, 0, 0, 0);
            c = __builtin_amdgcn_mfma_f32_16x16x32_bf16(a2, b2, c, 0, 0, 0);
            c = __builtin_amdgcn_mfma_f32_16x16x32_bf16(a3, b3, c, 0, 0, 0);
            const int h = lrow;
            if (h < HH) {
                #pragma unroll
                for (int rg = 0; rg < 4; ++rg) {
                    const int row = w*16 + kg*4 + rg;
                    sm.a.attn[h][row] = (c[rg] + sm.a.qkb[h]) * 0.25f + sm.a.maskadd[row];
                }
            }
        }
        __syncthreads();

        if (t < 64) {
            int h = t >> 3, l2 = t & 7;
            float mx = -3e38f;
            #pragma unroll
            for (int i = 0; i < 7; ++i) { int s = i*8 + l2; if (s < SS) mx = fmaxf(mx, sm.a.attn[h][s]); }
            mx = fmaxf(mx, __shfl_xor(mx, 1));
            mx = fmaxf(mx, __shfl_xor(mx, 2));
            mx = fmaxf(mx, __shfl_xor(mx, 4));
            float ev[7]; float sm_ = 0.f;
            #pragma unroll
            for (int i = 0; i < 7; ++i) {
                int s = i*8 + l2; ev[i] = 0.f;
                if (s < SS) { ev[i] = expf(sm.a.attn[h][s] - mx); sm_ += ev[i]; }
            }
            sm_ += __shfl_xor(sm_, 1);
            sm_ += __shfl_xor(sm_, 2);
            sm_ += __shfl_xor(sm_, 4);
            float inv = 1.f / sm_;
            #pragma unroll
            for (int i = 0; i < 7; ++i) { int s = i*8 + l2; if (s < SS) sm.a.attn[h][s] = ev[i] * inv; }
        }
        __syncthreads();

        f32x4 acc[8];
        #pragma unroll
        for (int nt = 0; nt < 8; ++nt) {
            const unsigned short* bp = p.wvT + (nt*16 + lrow)*EE + kg*8;
            bf16x8 b0 = *(const bf16x8*)&bp[0];
            bf16x8 b1 = *(const bf16x8*)&bp[32];
            bf16x8 b2 = *(const bf16x8*)&bp[64];
            bf16x8 b3 = *(const bf16x8*)&bp[96];
            f32x4 c = {0.f, 0.f, 0.f, 0.f};
            c = __builtin_amdgcn_mfma_f32_16x16x32_bf16(a0, b0, c, 0, 0, 0);
            c = __builtin_amdgcn_mfma_f32_16x16x32_bf16(a1, b1, c, 0, 0, 0);
            c = __builtin_amdgcn_mfma_f32_16x16x32_bf16(a2, b2, c, 0, 0, 0);
            c = __builtin_amdgcn_mfma_f32_16x16x32_bf16(a3, b3, c, 0, 0, 0);
            acc[nt] = c;
        }
        #pragma unroll
        for (int nt = 0; nt < 8; ++nt) {
            const int col = nt*16 + lrow;
            const float bvc = p.bv[col];
            #pragma unroll
            for (int rg = 0; rg < 4; ++rg) {
                const int row = w*16 + kg*4 + rg;
                const float av = (row < SS) ? sm.a.attn[nt][row] : 0.f;
                sm.a.kA[row*LDK + col] = f2bf((acc[nt][rg] + bvc) * av);
            }
        }
        __syncthreads();

        bf16x8 c0 = *(const bf16x8*)&sm.a.kA[(w*16 + lrow)*LDK +  0 + kg*8];
        bf16x8 c1 = *(const bf16x8*)&sm.a.kA[(w*16 + lrow)*LDK + 32 + kg*8];
        bf16x8 c2 = *(const bf16x8*)&sm.a.kA[(w*16 + lrow)*LDK + 64 + kg*8];
        bf16x8 c3 = *(const bf16x8*)&sm.a.kA[(w*16 + lrow)*LDK + 96 + kg*8];

        #pragma unroll
        for (int nt = 0; nt < 8; ++nt) {
            const unsigned short* bp = p.woT + (nt*16 + lrow)*EE + kg*8;
            bf16x8 b0 = *(const bf16x8*)&bp[0];
            bf16x8 b1 = *(const bf16x8*)&bp[32];
            bf16x8 b2 = *(const bf16x8*)&bp[64];
            bf16x8 b3 = *(const bf16x8*)&bp[96];
            f32x4 c = {0.f, 0.f, 0.f, 0.f};
            c = __builtin_amdgcn_mfma_f32_16x16x32_bf16(c0, b0, c, 0, 0, 0);
            c = __builtin_amdgcn_mfma_f32_16x16x32_bf16(c1, b1, c, 0, 0, 0);
            c = __builtin_amdgcn_mfma_f32_16x16x32_bf16(c2, b2, c, 0, 0, 0);
            c = __builtin_amdgcn_mfma_f32_16x16x32_bf16(c3, b3, c, 0, 0, 0);
            const int col = nt*16 + lrow;
            const float boc = p.bo[col];
            #pragma unroll
            for (int rg = 0; rg < 4; ++rg) {
                const int row = w*16 + kg*4 + rg;
                if (row < SS)
                    p.ws_ne2[((size_t)b*SS + row)*EE + col] = c[rg] + boc;
            }
        }
    } else {
        // ---------------- ip-half region: blocks 512..767 stride the j-list ----------------
        const int M = p.Mcount[0];
        for (int c = bid - BB; c < M; c += GRID - BB) {
            const int j  = p.jlist[c];
            const int s0 = p.jstart[c], s1 = p.jstart[c + 1];
            const f32x4* kp = (const f32x4*)(p.ui_lcu + ((size_t)j*RR + r)*EE);
            f32x4 P0 = kp[l], P1 = kp[l+8], P2 = kp[l+16], P3 = kp[l+24];
            for (int o = s0; o < s1; ++o) {
                const f32x4* rp = (const f32x4*)(p.iet + (size_t)p.pitem[o]*EE);
                float acc = dot44(P0, rp[l]) + dot44(P1, rp[l+8])
                          + dot44(P2, rp[l+16]) + dot44(P3, rp[l+24]);
                acc += __shfl_xor(acc, 1); acc += __shfl_xor(acc, 2); acc += __shfl_xor(acc, 4);
                if (l == 0) {
                    const int bs = p.pinfo[o] & 0xFFFF;
                    p.ws_ip[(size_t)bs*RR + r] = acc;
                }
            }
        }
    }
    grid.sync();

    // ================= P5: np-half region — all blocks stride the j-list =================
    {
        const int M = p.Mcount[0];
        for (int c = bid; c < M; c += GRID) {
            const int j  = p.jlist[c];
            const int s0 = p.jstart[c], s1 = p.jstart[c + 1];
            const f32x4* kp = (const f32x4*)(p.iu_lcu + ((size_t)j*RR + r)*EE);
            f32x4 P0 = kp[l], P1 = kp[l+8], P2 = kp[l+16], P3 = kp[l+24];
            for (int o = s0; o < s1; ++o) {
                const int info = p.pinfo[o];
                const int bs = info & 0xFFFF;
                const f32x4* rp = (const f32x4*)(p.ws_ne2 + (size_t)bs*EE);
                float acc = dot44(P0, rp[l]) + dot44(P1, rp[l+8])
                          + dot44(P2, rp[l+16]) + dot44(P3, rp[l+24]);
                acc += __shfl_xor(acc, 1); acc += __shfl_xor(acc, 2); acc += __shfl_xor(acc, 4);
                if (l == 0)
                    p.ws_np[(size_t)bs*RR + r] = (info < 0) ? 0.f : acc;
            }
        }
    }
    grid.sync();

    // ================= P6: head — max over s of np*ip, FC, softmax =================
    if (bid < BB) {
        const int b = bid;
        const int rr = t & 31, sub = t >> 5;
        float m = -3e38f;
        for (int s = sub; s < SS; s += 8) {
            const size_t idx = ((size_t)b*SS + s)*RR + rr;
            m = fmaxf(m, p.ws_np[idx] * p.ws_ip[idx]);
        }
        sm.h.part[sub][rr] = m;
        __syncthreads();
        if (t < RR) {
            float mm = sm.h.part[0][t];
            #pragma unroll
            for (int k = 1; k < 8; ++k) mm = fmaxf(mm, sm.h.part[k][t]);
            sm.h.urv[t] = mm;
        }
        __syncthreads();
        if (t < NC) {
            float acc = p.fcb[t];
            #pragma unroll
            for (int q = 0; q < RR; ++q) acc = fmaf(sm.h.urv[q], p.fcw[q*NC + t], acc);
            sm.h.lg[t] = acc;
        }
        __syncthreads();
        if (t < NC) {
            float mx = sm.h.lg[0];
            #pragma unroll
            for (int cc = 1; cc < NC; ++cc) mx = fmaxf(mx, sm.h.lg[cc]);
            float s = 0.f;
            #pragma unroll
            for (int cc = 0; cc < NC; ++cc) s += expf(sm.h.lg[cc] - mx);
            p.out[b*NC + t] = expf(sm.h.lg[t] - mx) / s;
        }
    }
}

extern "C" void kernel_launch(void* const* d_in, const int* in_sizes, int n_in,
                              void* d_out, int out_size, void* d_ws, size_t ws_size,
                              hipStream_t stream) {
    Params P;
    P.user     = (const int*)d_in[0];
    P.item     = (const int*)d_in[1];
    P.neighbor = (const int*)d_in[2];
    P.seq      = (const int*)d_in[3];
    P.uet      = (const float*)d_in[4];
    P.iet      = (const float*)d_in[5];
    P.ui_lcu   = (const float*)d_in[6];
    P.iu_lcu   = (const float*)d_in[7];
    P.wq = (const float*)d_in[8];   P.bq = (const float*)d_in[9];
    P.wk = (const float*)d_in[10];  P.bk = (const float*)d_in[11];
    P.wv = (const float*)d_in[12];  P.bv = (const float*)d_in[13];
    P.wo = (const float*)d_in[14];  P.bo = (const float*)d_in[15];
    P.fcw = (const float*)d_in[16]; P.fcb = (const float*)d_in[17];

    float* ws = (float*)d_ws;
    P.ws_ne2 = ws;                                        // B*S*E f32
    P.ws_np  = P.ws_ne2 + (size_t)BB*SS*EE;               // NBS*R f32
    P.ws_ip  = P.ws_np  + (size_t)NBS*RR;                 // NBS*R f32
    P.wvT    = (unsigned short*)(P.ws_ip + (size_t)NBS*RR);   // 128*128 bf16
    P.woT    = P.wvT + EE*EE;                             // 128*128 bf16
    P.hist   = (int*)(P.woT + EE*EE);                     // NSEQ
    P.jlist  = P.hist + NSEQ;                             // NSEQ
    P.jstart = P.jlist + NSEQ;                            // NSEQ+1
    P.Mcount = P.jstart + NSEQ + 1;                       // 1 (+pad)
    P.pinfo  = P.Mcount + 4;                              // NBS
    P.pitem  = P.pinfo + NBS;                             // NBS
    P.blockSum = P.pitem + NBS;                           // SCANB (+pad)
    P.blockNz  = P.blockSum + 128;                        // SCANB
    P.out    = (float*)d_out;

    void* args[] = { &P };
    hipLaunchCooperativeKernel((void*)mega_kernel, dim3(GRID), dim3(256),
                               args, 0, stream);
}

// Round 11
// 196.503 us; speedup vs baseline: 4.7497x; 4.7497x over previous
//
#include <hip/hip_runtime.h>
#include <math.h>

#define BB 512
#define SS 50
#define EE 128
#define HH 8
#define RR 32
#define NC 5
#define NSEQ 20000
#define NBS (BB*SS)   // 25600
#define LDK 136       // padded bf16 row stride (ushorts) for LDS A-tile

typedef __attribute__((ext_vector_type(8))) __bf16 bf16x8;
typedef __attribute__((ext_vector_type(4))) float f32x4;
typedef __attribute__((ext_vector_type(4))) unsigned short us4;

__device__ __forceinline__ unsigned short f2bf(float f) {
    unsigned int u = __float_as_uint(f);
    unsigned int r = (u + 0x7fffu + ((u >> 16) & 1u)) >> 16;
    return (unsigned short)r;
}
__device__ __forceinline__ float dot44(const f32x4& a, const f32x4& b) {
    return a[0]*b[0] + a[1]*b[1] + a[2]*b[2] + a[3]*b[3];
}

// -------------------- prep: weight transpose/convert + seq histogram --------------------
__global__ __launch_bounds__(256) void prep_kernel(const float* __restrict__ wv,
                                                   const float* __restrict__ wo,
                                                   unsigned short* __restrict__ wvT,
                                                   unsigned short* __restrict__ woT,
                                                   const int* __restrict__ seq,
                                                   int* __restrict__ hist) {
    const int bid = blockIdx.x, t = threadIdx.x;
    if (bid < 128) {
        const int n = bid;
        if (t < 128) wvT[n*EE + t] = f2bf(wv[t*EE + n]);
        else         woT[n*EE + (t - 128)] = f2bf(wo[(t - 128)*EE + n]);
    } else {
        const int i = (bid - 128) * 256 + t;
        if (i < NBS) atomicAdd(&hist[seq[i]], 1);
    }
}

// single block, 1024 threads: exclusive scan of hist[NSEQ] in place (scatter offsets)
__global__ __launch_bounds__(1024) void scan_kernel(int* __restrict__ hist) {
    const int t = threadIdx.x;
    const int CH = 20;                      // 1024*20 >= NSEQ
    const int base = t * CH;
    int loc[CH];
    int s = 0;
    #pragma unroll
    for (int i = 0; i < CH; ++i) {
        int idx = base + i;
        int v = (idx < NSEQ) ? hist[idx] : 0;
        loc[i] = s; s += v;
    }
    const int lane = t & 63, w = t >> 6;    // 16 waves
    int incl = s;
    #pragma unroll
    for (int off = 1; off < 64; off <<= 1) {
        int n = __shfl_up(incl, off);
        if (lane >= off) incl += n;
    }
    __shared__ int wsum[16];
    if (lane == 63) wsum[w] = incl;
    __syncthreads();
    if (t == 0) {
        int acc = 0;
        #pragma unroll
        for (int k = 0; k < 16; ++k) { int v = wsum[k]; wsum[k] = acc; acc += v; }
    }
    __syncthreads();
    const int excl = incl - s + wsum[w];
    #pragma unroll
    for (int i = 0; i < CH; ++i) {
        int idx = base + i;
        if (idx < NSEQ) hist[idx] = excl + loc[i];
    }
}

// scatter: group (b,s) by seq value; precompute POSITION-ORDER j / bs|mask / item-row
__global__ __launch_bounds__(256) void scatter_kernel(const int* __restrict__ seq,
                                                      const int* __restrict__ neighbor,
                                                      const int* __restrict__ item,
                                                      int* __restrict__ hist,
                                                      int* __restrict__ pseq,
                                                      int* __restrict__ pinfo,
                                                      int* __restrict__ pitem) {
    int i = blockIdx.x * 256 + threadIdx.x;
    if (i < NBS) {
        const int j = seq[i];
        int pos = atomicAdd(&hist[j], 1);
        pseq[pos]  = j;
        pinfo[pos] = i | ((neighbor[i] > 0) ? 0 : 0x80000000);
        pitem[pos] = item[(unsigned)i / SS];
    }
}

// -------------------- Kernel 1: attention, all-MFMA (verified r6 code) --------------------
__global__ __launch_bounds__(256, 4) void attn_kernel(
    const int* __restrict__ user,
    const int* __restrict__ neighbor,
    const float* __restrict__ uet,
    const float* __restrict__ wq, const float* __restrict__ bq,
    const float* __restrict__ wk, const float* __restrict__ bk,
    const float* __restrict__ bv, const float* __restrict__ bo,
    const unsigned short* __restrict__ wvT, const unsigned short* __restrict__ woT,
    float* __restrict__ ws_ne2)
{
    __shared__ unsigned short kA[64*LDK];
    __shared__ unsigned short qkvT[16][EE];
    __shared__ float ue[EE];
    __shared__ float qs[EE];
    __shared__ float qkb[HH];
    __shared__ float attn_s[HH][64];
    __shared__ float maskadd[64];

    const int b = blockIdx.x;
    const int t = threadIdx.x;

    if (t < EE) ue[t] = uet[(size_t)user[b]*EE + t];
    if (t < 64) maskadd[t] = (t < SS && neighbor[b*SS + t] > 0) ? 0.f : -1e9f;
    for (int idx = t; idx < SS*32; idx += 256) {
        int s = idx >> 5, g = idx & 31;
        float4 v = ((const float4*)(uet + (size_t)neighbor[b*SS + s]*EE))[g];
        us4 o; o.x = f2bf(v.x); o.y = f2bf(v.y); o.z = f2bf(v.z); o.w = f2bf(v.w);
        *(us4*)&kA[s*LDK + g*4] = o;
    }
    for (int idx = t; idx < 14*LDK; idx += 256) kA[50*LDK + idx] = 0;
    for (int idx = t; idx < 8*EE; idx += 256) qkvT[8 + (idx >> 7)][idx & 127] = 0;
    __syncthreads();

    if (t < EE) {
        float acc = bq[t];
        #pragma unroll 4
        for (int e = 0; e < EE; ++e) acc = fmaf(ue[e], wq[e*EE + t], acc);
        qs[t] = acc;
    }
    __syncthreads();

    {
        const int e = t >> 1, h0 = (t & 1) * 4;
        const float* wrow = wk + e*EE;
        #pragma unroll
        for (int j = 0; j < 4; ++j) {
            int h = h0 + j;
            float acc = 0.f;
            #pragma unroll
            for (int d = 0; d < 16; ++d) acc = fmaf(qs[h*16 + d], wrow[h*16 + d], acc);
            qkvT[h][e] = f2bf(acc);
        }
    }
    if (t < HH) {
        float acc = 0.f;
        #pragma unroll
        for (int d = 0; d < 16; ++d) acc = fmaf(qs[t*16 + d], bk[t*16 + d], acc);
        qkb[t] = acc;
    }
    __syncthreads();

    const int w    = t >> 6;
    const int l    = t & 63;
    const int lrow = l & 15;
    const int kg   = l >> 4;

    bf16x8 a0 = *(const bf16x8*)&kA[(w*16 + lrow)*LDK +  0 + kg*8];
    bf16x8 a1 = *(const bf16x8*)&kA[(w*16 + lrow)*LDK + 32 + kg*8];
    bf16x8 a2 = *(const bf16x8*)&kA[(w*16 + lrow)*LDK + 64 + kg*8];
    bf16x8 a3 = *(const bf16x8*)&kA[(w*16 + lrow)*LDK + 96 + kg*8];

    {
        bf16x8 b0 = *(const bf16x8*)&qkvT[lrow][ 0 + kg*8];
        bf16x8 b1 = *(const bf16x8*)&qkvT[lrow][32 + kg*8];
        bf16x8 b2 = *(const bf16x8*)&qkvT[lrow][64 + kg*8];
        bf16x8 b3 = *(const bf16x8*)&qkvT[lrow][96 + kg*8];
        f32x4 c = {0.f, 0.f, 0.f, 0.f};
        c = __builtin_amdgcn_mfma_f32_16x16x32_bf16(a0, b0, c, 0, 0, 0);
        c = __builtin_amdgcn_mfma_f32_16x16x32_bf16(a1, b1, c, 0, 0, 0);
        c = __builtin_amdgcn_mfma_f32_16x16x32_bf16(a2, b2, c, 0, 0, 0);
        c = __builtin_amdgcn_mfma_f32_16x16x32_bf16(a3, b3, c, 0, 0, 0);
        const int h = lrow;
        if (h < HH) {
            #pragma unroll
            for (int rg = 0; rg < 4; ++rg) {
                const int row = w*16 + kg*4 + rg;
                attn_s[h][row] = (c[rg] + qkb[h]) * 0.25f + maskadd[row];
            }
        }
    }
    __syncthreads();

    if (t < 64) {
        int h = t >> 3, ll = t & 7;
        float mx = -3e38f;
        #pragma unroll
        for (int i = 0; i < 7; ++i) { int s = i*8 + ll; if (s < SS) mx = fmaxf(mx, attn_s[h][s]); }
        mx = fmaxf(mx, __shfl_xor(mx, 1));
        mx = fmaxf(mx, __shfl_xor(mx, 2));
        mx = fmaxf(mx, __shfl_xor(mx, 4));
        float ev[7]; float sm_ = 0.f;
        #pragma unroll
        for (int i = 0; i < 7; ++i) {
            int s = i*8 + ll; ev[i] = 0.f;
            if (s < SS) { ev[i] = expf(attn_s[h][s] - mx); sm_ += ev[i]; }
        }
        sm_ += __shfl_xor(sm_, 1);
        sm_ += __shfl_xor(sm_, 2);
        sm_ += __shfl_xor(sm_, 4);
        float inv = 1.f / sm_;
        #pragma unroll
        for (int i = 0; i < 7; ++i) { int s = i*8 + ll; if (s < SS) attn_s[h][s] = ev[i] * inv; }
    }
    __syncthreads();

    f32x4 acc[8];
    #pragma unroll
    for (int nt = 0; nt < 8; ++nt) {
        const unsigned short* bp = wvT + (nt*16 + lrow)*EE + kg*8;
        bf16x8 b0 = *(const bf16x8*)&bp[0];
        bf16x8 b1 = *(const bf16x8*)&bp[32];
        bf16x8 b2 = *(const bf16x8*)&bp[64];
        bf16x8 b3 = *(const bf16x8*)&bp[96];
        f32x4 c = {0.f, 0.f, 0.f, 0.f};
        c = __builtin_amdgcn_mfma_f32_16x16x32_bf16(a0, b0, c, 0, 0, 0);
        c = __builtin_amdgcn_mfma_f32_16x16x32_bf16(a1, b1, c, 0, 0, 0);
        c = __builtin_amdgcn_mfma_f32_16x16x32_bf16(a2, b2, c, 0, 0, 0);
        c = __builtin_amdgcn_mfma_f32_16x16x32_bf16(a3, b3, c, 0, 0, 0);
        acc[nt] = c;
    }
    #pragma unroll
    for (int nt = 0; nt < 8; ++nt) {
        const int col = nt*16 + lrow;
        const float bvc = bv[col];
        #pragma unroll
        for (int rg = 0; rg < 4; ++rg) {
            const int row = w*16 + kg*4 + rg;
            const float av = (row < SS) ? attn_s[nt][row] : 0.f;
            kA[row*LDK + col] = f2bf((acc[nt][rg] + bvc) * av);
        }
    }
    __syncthreads();

    bf16x8 c0 = *(const bf16x8*)&kA[(w*16 + lrow)*LDK +  0 + kg*8];
    bf16x8 c1 = *(const bf16x8*)&kA[(w*16 + lrow)*LDK + 32 + kg*8];
    bf16x8 c2 = *(const bf16x8*)&kA[(w*16 + lrow)*LDK + 64 + kg*8];
    bf16x8 c3 = *(const bf16x8*)&kA[(w*16 + lrow)*LDK + 96 + kg*8];

    #pragma unroll
    for (int nt = 0; nt < 8; ++nt) {
        const unsigned short* bp = woT + (nt*16 + lrow)*EE + kg*8;
        bf16x8 b0 = *(const bf16x8*)&bp[0];
        bf16x8 b1 = *(const bf16x8*)&bp[32];
        bf16x8 b2 = *(const bf16x8*)&bp[64];
        bf16x8 b3 = *(const bf16x8*)&bp[96];
        f32x4 c = {0.f, 0.f, 0.f, 0.f};
        c = __builtin_amdgcn_mfma_f32_16x16x32_bf16(c0, b0, c, 0, 0, 0);
        c = __builtin_amdgcn_mfma_f32_16x16x32_bf16(c1, b1, c, 0, 0, 0);
        c = __builtin_amdgcn_mfma_f32_16x16x32_bf16(c2, b2, c, 0, 0, 0);
        c = __builtin_amdgcn_mfma_f32_16x16x32_bf16(c3, b3, c, 0, 0, 0);
        const int col = nt*16 + lrow;
        const float boc = bo[col];
        #pragma unroll
        for (int rg = 0; rg < 4; ++rg) {
            const int row = w*16 + kg*4 + rg;
            if (row < SS)
                ws_ne2[((size_t)b*SS + row)*EE + col] = c[rg] + boc;
        }
    }
}

// -------------------- Kernel 2: region — one block per SORTED position o --------------------
// 25600 independent blocks; 3 int loads -> 16 vector loads, no LDS, no barrier, max MLP
__global__ __launch_bounds__(256, 6) void region_kernel(
    const float* __restrict__ iu_lcu, const float* __restrict__ ui_lcu,
    const float* __restrict__ ws_ne2, const float* __restrict__ iet,
    const int* __restrict__ pseq, const int* __restrict__ pinfo,
    const int* __restrict__ pitem,
    float* __restrict__ ws_np, float* __restrict__ ws_ip)
{
    const int o = blockIdx.x;
    const int t = threadIdx.x, r = t >> 3, l = t & 7;
    const int j    = pseq[o];
    const int info = pinfo[o];
    const int bs   = info & 0xFFFF;
    const int it   = pitem[o];

    const f32x4* kiu = (const f32x4*)(iu_lcu + ((size_t)j*RR + r)*EE);
    const f32x4* kui = (const f32x4*)(ui_lcu + ((size_t)j*RR + r)*EE);
    const f32x4* nr  = (const f32x4*)(ws_ne2 + (size_t)bs*EE);
    const f32x4* ir  = (const f32x4*)(iet + (size_t)it*EE);

    float np = 0.f, ip = 0.f;
    #pragma unroll
    for (int i = 0; i < 4; ++i) {
        const int c = l + 8*i;
        np += dot44(kiu[c], nr[c]);
        ip += dot44(kui[c], ir[c]);
    }
    np += __shfl_xor(np, 1); np += __shfl_xor(np, 2); np += __shfl_xor(np, 4);
    ip += __shfl_xor(ip, 1); ip += __shfl_xor(ip, 2); ip += __shfl_xor(ip, 4);
    if (l == 0) {
        ws_np[(size_t)bs*RR + r] = (info < 0) ? 0.f : np;
        ws_ip[(size_t)bs*RR + r] = ip;
    }
}

// -------------------- Kernel 3: max over s of np*ip, FC, softmax --------------------
__global__ __launch_bounds__(256) void head_kernel(
    const float* __restrict__ ws_np, const float* __restrict__ ws_ip,
    const float* __restrict__ fc_w, const float* __restrict__ fc_b,
    float* __restrict__ out)
{
    __shared__ float part[8][RR];
    __shared__ float urv[RR];
    __shared__ float lg[NC];
    const int b = blockIdx.x, t = threadIdx.x;
    const int r = t & 31, sub = t >> 5;

    float m = -3e38f;
    for (int s = sub; s < SS; s += 8) {
        const size_t idx = ((size_t)b*SS + s)*RR + r;
        m = fmaxf(m, ws_np[idx] * ws_ip[idx]);
    }
    part[sub][r] = m;
    __syncthreads();
    if (t < RR) {
        float mm = part[0][t];
        #pragma unroll
        for (int k = 1; k < 8; ++k) mm = fmaxf(mm, part[k][t]);
        urv[t] = mm;
    }
    __syncthreads();
    if (t < NC) {
        float acc = fc_b[t];
        #pragma unroll
        for (int rr = 0; rr < RR; ++rr) acc = fmaf(urv[rr], fc_w[rr*NC + t], acc);
        lg[t] = acc;
    }
    __syncthreads();
    if (t < NC) {
        float mx = lg[0];
        #pragma unroll
        for (int cc = 1; cc < NC; ++cc) mx = fmaxf(mx, lg[cc]);
        float sm = 0.f;
        #pragma unroll
        for (int cc = 0; cc < NC; ++cc) sm += expf(lg[cc] - mx);
        out[b*NC + t] = expf(lg[t] - mx) / sm;
    }
}

extern "C" void kernel_launch(void* const* d_in, const int* in_sizes, int n_in,
                              void* d_out, int out_size, void* d_ws, size_t ws_size,
                              hipStream_t stream) {
    const int*   user     = (const int*)d_in[0];
    const int*   item     = (const int*)d_in[1];
    const int*   neighbor = (const int*)d_in[2];
    const int*   seq      = (const int*)d_in[3];
    const float* uet      = (const float*)d_in[4];
    const float* iet      = (const float*)d_in[5];
    const float* ui_lcu   = (const float*)d_in[6];
    const float* iu_lcu   = (const float*)d_in[7];
    const float* wq = (const float*)d_in[8];   const float* bq = (const float*)d_in[9];
    const float* wk = (const float*)d_in[10];  const float* bk = (const float*)d_in[11];
    const float* wv = (const float*)d_in[12];  const float* bv = (const float*)d_in[13];
    const float* wo = (const float*)d_in[14];  const float* bo = (const float*)d_in[15];
    const float* fcw = (const float*)d_in[16]; const float* fcb = (const float*)d_in[17];

    float* ws = (float*)d_ws;
    float* ws_ne2 = ws;                                          // B*S*E f32
    float* ws_np  = ws_ne2 + (size_t)BB*SS*EE;                   // NBS*R f32
    float* ws_ip  = ws_np  + (size_t)NBS*RR;                     // NBS*R f32
    unsigned short* wvT = (unsigned short*)(ws_ip + (size_t)NBS*RR);  // 128*128 bf16
    unsigned short* woT = wvT + EE*EE;                           // 128*128 bf16
    int* hist  = (int*)(woT + EE*EE);                            // NSEQ (working offsets)
    int* pseq  = hist + NSEQ;                                    // NBS (j per sorted pos)
    int* pinfo = pseq + NBS;                                     // NBS (bs | mask<<31)
    int* pitem = pinfo + NBS;                                    // NBS (item row)
    float* out = (float*)d_out;

    // ---- prep: conv + hist (fused), scan, scatter ----
    hipMemsetAsync(hist, 0, NSEQ * sizeof(int), stream);
    hipLaunchKernelGGL(prep_kernel, dim3(128 + (NBS + 255)/256), dim3(256), 0, stream,
                       wv, wo, wvT, woT, seq, hist);
    hipLaunchKernelGGL(scan_kernel, dim3(1), dim3(1024), 0, stream, hist);
    hipLaunchKernelGGL(scatter_kernel, dim3((NBS + 255)/256), dim3(256), 0, stream,
                       seq, neighbor, item, hist, pseq, pinfo, pitem);

    // ---- attention (all-MFMA) ----
    hipLaunchKernelGGL(attn_kernel, dim3(BB), dim3(256), 0, stream,
                       user, neighbor, uet,
                       wq, bq, wk, bk, bv, bo, wvT, woT, ws_ne2);

    // ---- region: one block per sorted occurrence, both halves, barrier-free ----
    hipLaunchKernelGGL(region_kernel, dim3(NBS), dim3(256), 0, stream,
                       iu_lcu, ui_lcu, ws_ne2, iet,
                       pseq, pinfo, pitem, ws_np, ws_ip);

    hipLaunchKernelGGL(head_kernel, dim3(BB), dim3(256), 0, stream,
                       ws_np, ws_ip, fcw, fcb, out);
}